// Round 15
// baseline (139.221 us; speedup 1.0000x reference)
//
#include <hip/hip_runtime.h>

#define LN_EPS 1e-5f

// Sizes fixed by the problem: B=32, TF=2048, C=32, D=8, HID=EG=32.
// rows = B*TF*C = 2,097,152 independent rows: x[8] -> M1x+c1 -> relu -> LN ->
// M2'h+c2' -> relu -> LN -> *g2+be2. Adjacency + LN1 affine folded on device.
//
// PROVEN-ROLE RULE (r6-r11): MFMA arg0 = activation fragments read row-wise
// from LDS (r5 pattern); arg1 = baked weight table. Do not swap.
// PRECISION RULE (r12): full 3-term hi/lo split required (2-term = 0.219 absmax).
// r14: XOR-swizzled 8 KB per-wave LDS (bank-floor), 5 blocks/CU. Passed.
// r15: workgroup = ONE wave (64 threads): barriers become wave-local waits
// (no 4-wave convoy); 20 independent blocks/CU. Math bit-identical to r14.
//
// d_ws float layout:
//   [0,256)     M1pk: pair-interleaved M1, ws[p*16 + d*2 + e] = M1[2p+e][d]
//   [256,288)   c1  = A@b1   (pairs read as float2)
//   [1312,1344) c2' = A@b2 + (A@W2)@be1
//   [1344,1376) g2
//   [1376,1408) be2
//   u16 [2816,3840)  B-frag bhi: slot (nt*64 + l15*4 + lg)*8+i =
//                    bf16hi(M2'[n=nt*16+l15][k=lg*8+i]),  M2'=(A@W2)*diag(g1)
//   u16 [3840,4864)  B-frag blo: bf16lo residual of the same

typedef float  f32x4  __attribute__((ext_vector_type(4)));
typedef __bf16 bf16x8 __attribute__((ext_vector_type(8)));

__global__ void gnn_prologue(const float* __restrict__ adjacency,
                             const float* __restrict__ W1,
                             const float* __restrict__ b1,
                             const float* __restrict__ W2,
                             const float* __restrict__ b2,
                             const float* __restrict__ g1,
                             const float* __restrict__ be1,
                             const float* __restrict__ g2,
                             const float* __restrict__ be2,
                             float* __restrict__ ws) {
    __shared__ float dis[32];
    __shared__ float na[32][32];
    __shared__ float m2t[32][32];   // A@W2 (g1 folded at bake)
    __shared__ float m1s[32][8];
    const int t = threadIdx.x;
    if (t < 32) {
        float s = 1.0f;  // self-loop contributes 1 to the degree
        for (int j = 0; j < 32; ++j) s += adjacency[t * 32 + j];
        dis[t] = rsqrtf(s + 1e-6f);
    }
    __syncthreads();
    for (int idx = t; idx < 1024; idx += 256) {
        const int i = idx >> 5, j = idx & 31;
        const float a = adjacency[idx] + (i == j ? 1.0f : 0.0f);
        na[i][j] = dis[i] * a * dis[j];
    }
    __syncthreads();
    for (int idx = t; idx < 1024; idx += 256) {     // m2t = na @ W2
        const int i = idx >> 5, k = idx & 31;
        float a = 0.0f;
        for (int j = 0; j < 32; ++j) a += na[i][j] * W2[j * 32 + k];
        m2t[i][k] = a;
    }
    {
        const int i = t >> 3, d = t & 7;            // m1 = na @ W1 (to LDS)
        float a = 0.0f;
        for (int j = 0; j < 32; ++j) a += na[i][j] * W1[j * 8 + d];
        m1s[i][d] = a;
    }
    __syncthreads();
    if (t < 128) {                                   // M1 pk-interleaved bake
        const int p = t >> 3, d = t & 7;
        ws[p * 16 + d * 2]     = m1s[2 * p][d];
        ws[p * 16 + d * 2 + 1] = m1s[2 * p + 1][d];
    }
    if (t < 32) {
        float a1 = 0.0f, a2 = 0.0f, a3 = 0.0f;
        for (int j = 0; j < 32; ++j) {
            a1 += na[t][j] * b1[j];
            a2 += na[t][j] * b2[j];
            a3 += m2t[t][j] * be1[j];
        }
        ws[256 + t]  = a1;          // c1
        ws[1312 + t] = a2 + a3;     // c2'
        ws[1344 + t] = g2[t];
        ws[1376 + t] = be2[t];
    }
    // Bake B fragments (r5-exact): slot (nt, l15, lg) holds k = lg*8+i for
    // n = nt*16 + l15, split into bf16 hi/lo.
    if (t < 128) {
        const int nt  = t >> 6;
        const int l15 = (t >> 2) & 15;
        const int lg  = t & 3;
        const int n   = nt * 16 + l15;
        unsigned short* wsu = (unsigned short*)ws;
        for (int i = 0; i < 8; ++i) {
            const float w  = m2t[n][lg * 8 + i] * g1[lg * 8 + i];
            const __bf16 h = (__bf16)w;
            const __bf16 l = (__bf16)(w - (float)h);
            wsu[2816 + t * 8 + i] = __builtin_bit_cast(unsigned short, h);
            wsu[3840 + t * 8 + i] = __builtin_bit_cast(unsigned short, l);
        }
    }
}

// Main kernel (r14 math, 1-wave workgroups): 64 threads = 1 wave = 64 rows.
// LDS = 2048 dwords (8 KB) per block, reused twice (wave-local sync):
//   phase A: hhat[row 0..63][32 dwords], slot c at r*32 + ((c ^ (r&7))<<2)
//   phase B: YT[n 0..31][64 dwords],     slot s at n*64 + ((s ^ (n&15))<<2)
// 20 blocks/CU (LDS), 5 waves/SIMD; no cross-wave barrier coupling.
__global__ __launch_bounds__(64, 5) void gnn_main(
        const float* __restrict__ x,
        const float* __restrict__ ws,
        float* __restrict__ out) {
    __shared__ __align__(16) float hb[2048];

    const int lane = threadIdx.x & 63;
    const int l15  = lane & 15;
    const int lg   = lane >> 4;

    // B fragments (weights as arg1 — PROVEN ROLE), baked bf16 hi/lo.
    const unsigned short* wsu = (const unsigned short*)ws;
    const int slot8 = (l15 * 4 + lg) * 8;
    bf16x8 bhi[2], blo[2];
    bhi[0] = *(const bf16x8*)(wsu + 2816 + slot8);
    bhi[1] = *(const bf16x8*)(wsu + 2816 + 512 + slot8);
    blo[0] = *(const bf16x8*)(wsu + 3840 + slot8);
    blo[1] = *(const bf16x8*)(wsu + 3840 + 512 + slot8);
    const float c2a = ws[1312 + l15];
    const float c2b = ws[1312 + 16 + l15];

    const int row_g = blockIdx.x * 64 + lane;   // one row per thread
    const float4 p0 = ((const float4*)x)[row_g * 2];
    const float4 p1 = ((const float4*)x)[row_g * 2 + 1];
    const float xr[8] = {p0.x, p0.y, p0.z, p0.w, p1.x, p1.y, p1.z, p1.w};

    // stage 1: h = relu(M1 @ x + c1) on float2 pairs (v_pk_fma_f32 pattern)
    float2 hp[16];
#pragma unroll
    for (int p = 0; p < 16; ++p) hp[p] = *(const float2*)(ws + 256 + p * 2);
#pragma unroll
    for (int d = 0; d < 8; ++d) {
        const float xd = xr[d];
#pragma unroll
        for (int p = 0; p < 16; ++p) {
            const float2 w = *(const float2*)(ws + p * 16 + d * 2);
            hp[p].x = fmaf(w.x, xd, hp[p].x);
            hp[p].y = fmaf(w.y, xd, hp[p].y);
        }
    }
#pragma unroll
    for (int p = 0; p < 16; ++p) {
        hp[p].x = fmaxf(hp[p].x, 0.0f);
        hp[p].y = fmaxf(hp[p].y, 0.0f);
    }
    // LN1 normalize (affine folded into M2'/c2'), paired tree moments
    {
        float2 sa = {0, 0}, sb = {0, 0}, qa = {0, 0}, qb = {0, 0};
#pragma unroll
        for (int p = 0; p < 16; p += 2) {
            sa.x += hp[p].x;     sa.y += hp[p].y;
            sb.x += hp[p + 1].x; sb.y += hp[p + 1].y;
            qa.x = fmaf(hp[p].x, hp[p].x, qa.x);
            qa.y = fmaf(hp[p].y, hp[p].y, qa.y);
            qb.x = fmaf(hp[p + 1].x, hp[p + 1].x, qb.x);
            qb.y = fmaf(hp[p + 1].y, hp[p + 1].y, qb.y);
        }
        const float m   = ((sa.x + sa.y) + (sb.x + sb.y)) * 0.03125f;
        const float msq = ((qa.x + qa.y) + (qb.x + qb.y)) * 0.03125f;
        const float r   = rsqrtf(fmaf(-m, m, msq) + LN_EPS);
        // phase A write: row = lane, slot c swizzled by (lane&7)
        float* const dst = hb + lane * 32;
        const int key3 = lane & 7;
#pragma unroll
        for (int c = 0; c < 8; ++c) {
            *(float4*)(dst + ((c ^ key3) << 2)) =
                make_float4((hp[c * 2].x - m) * r, (hp[c * 2].y - m) * r,
                            (hp[c * 2 + 1].x - m) * r, (hp[c * 2 + 1].y - m) * r);
        }
    }
    __syncthreads();   // wave-local: ordering only (1-wave workgroup)

    // A fragments (activations as arg0 — PROVEN ROLE): A[m][k]=hhat[mt*16+m][k];
    // lane holds m=l15, k=lg*8+i. Full hi/lo split (PRECISION RULE).
    bf16x8 ahi[4], alo[4];
    const int k7 = l15 & 7;   // row swizzle key: (mt*16+l15)&7 == l15&7
#pragma unroll
    for (int mt = 0; mt < 4; ++mt) {
        const float* ap = hb + (mt * 16 + l15) * 32;
        const float4 a0 = *(const float4*)(ap + (((2 * lg) ^ k7) << 2));
        const float4 a1 = *(const float4*)(ap + (((2 * lg + 1) ^ k7) << 2));
        const float av[8] = {a0.x, a0.y, a0.z, a0.w, a1.x, a1.y, a1.z, a1.w};
#pragma unroll
        for (int i = 0; i < 8; ++i) {
            const __bf16 hi = (__bf16)av[i];
            ahi[mt][i] = hi;
            alo[mt][i] = (__bf16)(av[i] - (float)hi);
        }
    }
    __syncthreads();   // wave-local: all A-frag reads landed before YT reuse

    // stage 2 MFMA: 4 m-tiles x 2 n-tiles, 3-term split; relu; YT write.
#pragma unroll
    for (int mt = 0; mt < 4; ++mt) {
#pragma unroll
        for (int nt = 0; nt < 2; ++nt) {
            const float c2v = nt ? c2b : c2a;
            f32x4 acc = {c2v, c2v, c2v, c2v};
            acc = __builtin_amdgcn_mfma_f32_16x16x32_bf16(ahi[mt], bhi[nt], acc, 0, 0, 0);
            acc = __builtin_amdgcn_mfma_f32_16x16x32_bf16(alo[mt], bhi[nt], acc, 0, 0, 0);
            acc = __builtin_amdgcn_mfma_f32_16x16x32_bf16(ahi[mt], blo[nt], acc, 0, 0, 0);
            // D reg j -> row (lane>>4)*4 + j, col lane&15  (r5-verified)
            float* yt = hb + (nt * 16 + l15) * 64 + (((mt * 4 + lg) ^ l15) << 2);
            *((float4*)yt) = make_float4(fmaxf(acc[0], 0.0f), fmaxf(acc[1], 0.0f),
                                         fmaxf(acc[2], 0.0f), fmaxf(acc[3], 0.0f));
        }
    }
    __syncthreads();   // wave-local

    // LN2 read-back: lane reads its own row m=lane (2 accesses/bank, free);
    // fused single-pass moments with tree partials.
    const int ms = lane >> 2, mo = lane & 3;
    float y[32];
#pragma unroll
    for (int c = 0; c < 32; ++c)
        y[c] = hb[c * 64 + ((ms ^ (c & 15)) << 2) + mo];
    float s0 = 0, s1 = 0, s2 = 0, s3 = 0, q0 = 0, q1 = 0, q2 = 0, q3 = 0;
#pragma unroll
    for (int i = 0; i < 32; i += 4) {
        s0 += y[i];     q0 = fmaf(y[i],     y[i],     q0);
        s1 += y[i + 1]; q1 = fmaf(y[i + 1], y[i + 1], q1);
        s2 += y[i + 2]; q2 = fmaf(y[i + 2], y[i + 2], q2);
        s3 += y[i + 3]; q3 = fmaf(y[i + 3], y[i + 3], q3);
    }
    const float m   = ((s0 + s1) + (s2 + s3)) * 0.03125f;
    const float msq = ((q0 + q1) + (q2 + q3)) * 0.03125f;
    const float r   = rsqrtf(fmaf(-m, m, msq) + LN_EPS);

    float4* ov = (float4*)out + (size_t)row_g * 8;
#pragma unroll
    for (int q = 0; q < 8; ++q) {
        ov[q] = make_float4(fmaf((y[q * 4 + 0] - m) * r, ws[1344 + q * 4 + 0], ws[1376 + q * 4 + 0]),
                            fmaf((y[q * 4 + 1] - m) * r, ws[1344 + q * 4 + 1], ws[1376 + q * 4 + 1]),
                            fmaf((y[q * 4 + 2] - m) * r, ws[1344 + q * 4 + 2], ws[1376 + q * 4 + 2]),
                            fmaf((y[q * 4 + 3] - m) * r, ws[1344 + q * 4 + 3], ws[1376 + q * 4 + 3]));
    }
}

extern "C" void kernel_launch(void* const* d_in, const int* in_sizes, int n_in,
                              void* d_out, int out_size, void* d_ws, size_t ws_size,
                              hipStream_t stream) {
    const float* x   = (const float*)d_in[0];
    const float* adj = (const float*)d_in[1];
    const float* W1  = (const float*)d_in[2];
    const float* b1  = (const float*)d_in[3];
    const float* W2  = (const float*)d_in[4];
    const float* b2  = (const float*)d_in[5];
    const float* g1  = (const float*)d_in[6];
    const float* be1 = (const float*)d_in[7];
    const float* g2  = (const float*)d_in[8];
    const float* be2 = (const float*)d_in[9];
    float* out = (float*)d_out;
    float* ws  = (float*)d_ws;

    gnn_prologue<<<1, 256, 0, stream>>>(adj, W1, b1, W2, b2, g1, be1, g2, be2, ws);

    const int rows = 32 * 2048 * 32;            // 2,097,152
    gnn_main<<<rows / 64, 64, 0, stream>>>(x, ws, out);
}

// Round 16
// 135.618 us; speedup vs baseline: 1.0266x; 1.0266x over previous
//
#include <hip/hip_runtime.h>

#define LN_EPS 1e-5f

// Sizes fixed by the problem: B=32, TF=2048, C=32, D=8, HID=EG=32.
// rows = B*TF*C = 2,097,152 independent rows: x[8] -> M1x+c1 -> relu -> LN ->
// M2'h+c2' -> relu -> LN -> *g2+be2. Adjacency + LN1 affine folded on device.
//
// PROVEN-ROLE RULE (r6-r11): MFMA arg0 = activation fragments read row-wise
// from LDS (r5 pattern); arg1 = baked weight table. Do not swap.
// PRECISION RULE (r12): full 3-term hi/lo split required (2-term = 0.219 absmax).
// r14: XOR-swizzled 8 KB per-wave LDS (bank-floor), 5x4-wave blocks/CU: 110.9us.
// r15 REGRESSION: 1-wave WGs hit the ~16 WG-slot/CU cap (16<20 waves): 139us.
// r16: 2-wave WGs (128 thr): 10 blocks/CU x 2 = 20 waves/CU, convoy width 2,
// WG-slot safe. Math bit-identical to r14.
//
// d_ws float layout:
//   [0,256)     M1pk: pair-interleaved M1, ws[p*16 + d*2 + e] = M1[2p+e][d]
//   [256,288)   c1  = A@b1   (pairs read as float2)
//   [1312,1344) c2' = A@b2 + (A@W2)@be1
//   [1344,1376) g2
//   [1376,1408) be2
//   u16 [2816,3840)  B-frag bhi: slot (nt*64 + l15*4 + lg)*8+i =
//                    bf16hi(M2'[n=nt*16+l15][k=lg*8+i]),  M2'=(A@W2)*diag(g1)
//   u16 [3840,4864)  B-frag blo: bf16lo residual of the same

typedef float  f32x4  __attribute__((ext_vector_type(4)));
typedef __bf16 bf16x8 __attribute__((ext_vector_type(8)));

__global__ void gnn_prologue(const float* __restrict__ adjacency,
                             const float* __restrict__ W1,
                             const float* __restrict__ b1,
                             const float* __restrict__ W2,
                             const float* __restrict__ b2,
                             const float* __restrict__ g1,
                             const float* __restrict__ be1,
                             const float* __restrict__ g2,
                             const float* __restrict__ be2,
                             float* __restrict__ ws) {
    __shared__ float dis[32];
    __shared__ float na[32][32];
    __shared__ float m2t[32][32];   // A@W2 (g1 folded at bake)
    __shared__ float m1s[32][8];
    const int t = threadIdx.x;
    if (t < 32) {
        float s = 1.0f;  // self-loop contributes 1 to the degree
        for (int j = 0; j < 32; ++j) s += adjacency[t * 32 + j];
        dis[t] = rsqrtf(s + 1e-6f);
    }
    __syncthreads();
    for (int idx = t; idx < 1024; idx += 256) {
        const int i = idx >> 5, j = idx & 31;
        const float a = adjacency[idx] + (i == j ? 1.0f : 0.0f);
        na[i][j] = dis[i] * a * dis[j];
    }
    __syncthreads();
    for (int idx = t; idx < 1024; idx += 256) {     // m2t = na @ W2
        const int i = idx >> 5, k = idx & 31;
        float a = 0.0f;
        for (int j = 0; j < 32; ++j) a += na[i][j] * W2[j * 32 + k];
        m2t[i][k] = a;
    }
    {
        const int i = t >> 3, d = t & 7;            // m1 = na @ W1 (to LDS)
        float a = 0.0f;
        for (int j = 0; j < 32; ++j) a += na[i][j] * W1[j * 8 + d];
        m1s[i][d] = a;
    }
    __syncthreads();
    if (t < 128) {                                   // M1 pk-interleaved bake
        const int p = t >> 3, d = t & 7;
        ws[p * 16 + d * 2]     = m1s[2 * p][d];
        ws[p * 16 + d * 2 + 1] = m1s[2 * p + 1][d];
    }
    if (t < 32) {
        float a1 = 0.0f, a2 = 0.0f, a3 = 0.0f;
        for (int j = 0; j < 32; ++j) {
            a1 += na[t][j] * b1[j];
            a2 += na[t][j] * b2[j];
            a3 += m2t[t][j] * be1[j];
        }
        ws[256 + t]  = a1;          // c1
        ws[1312 + t] = a2 + a3;     // c2'
        ws[1344 + t] = g2[t];
        ws[1376 + t] = be2[t];
    }
    // Bake B fragments (r5-exact): slot (nt, l15, lg) holds k = lg*8+i for
    // n = nt*16 + l15, split into bf16 hi/lo.
    if (t < 128) {
        const int nt  = t >> 6;
        const int l15 = (t >> 2) & 15;
        const int lg  = t & 3;
        const int n   = nt * 16 + l15;
        unsigned short* wsu = (unsigned short*)ws;
        for (int i = 0; i < 8; ++i) {
            const float w  = m2t[n][lg * 8 + i] * g1[lg * 8 + i];
            const __bf16 h = (__bf16)w;
            const __bf16 l = (__bf16)(w - (float)h);
            wsu[2816 + t * 8 + i] = __builtin_bit_cast(unsigned short, h);
            wsu[3840 + t * 8 + i] = __builtin_bit_cast(unsigned short, l);
        }
    }
}

// Main kernel (r14 math, 2-wave workgroups): 128 threads = 2 waves, 64 rows
// per wave. Per-wave LDS = 2048 dwords (8 KB), reused twice (barrier-sep):
//   phase A: hhat[row 0..63][32 dwords], slot c at r*32 + ((c ^ (r&7))<<2)
//   phase B: YT[n 0..31][64 dwords],     slot s at n*64 + ((s ^ (n&15))<<2)
// Block LDS = 16 KB -> 10 blocks/CU, 20 waves/CU, 2-wave barrier convoys.
__global__ __launch_bounds__(128, 5) void gnn_main(
        const float* __restrict__ x,
        const float* __restrict__ ws,
        float* __restrict__ out) {
    __shared__ __align__(16) float wbuf[2][2048];

    const int t    = threadIdx.x;
    const int wave = t >> 6;
    const int lane = t & 63;
    const int l15  = lane & 15;
    const int lg   = lane >> 4;
    float* const hb = wbuf[wave];

    // B fragments (weights as arg1 — PROVEN ROLE), baked bf16 hi/lo.
    const unsigned short* wsu = (const unsigned short*)ws;
    const int slot8 = (l15 * 4 + lg) * 8;
    bf16x8 bhi[2], blo[2];
    bhi[0] = *(const bf16x8*)(wsu + 2816 + slot8);
    bhi[1] = *(const bf16x8*)(wsu + 2816 + 512 + slot8);
    blo[0] = *(const bf16x8*)(wsu + 3840 + slot8);
    blo[1] = *(const bf16x8*)(wsu + 3840 + 512 + slot8);
    const float c2a = ws[1312 + l15];
    const float c2b = ws[1312 + 16 + l15];

    const int row_g = blockIdx.x * 128 + t;     // one row per thread
    const float4 p0 = ((const float4*)x)[row_g * 2];
    const float4 p1 = ((const float4*)x)[row_g * 2 + 1];
    const float xr[8] = {p0.x, p0.y, p0.z, p0.w, p1.x, p1.y, p1.z, p1.w};

    // stage 1: h = relu(M1 @ x + c1) on float2 pairs (v_pk_fma_f32 pattern)
    float2 hp[16];
#pragma unroll
    for (int p = 0; p < 16; ++p) hp[p] = *(const float2*)(ws + 256 + p * 2);
#pragma unroll
    for (int d = 0; d < 8; ++d) {
        const float xd = xr[d];
#pragma unroll
        for (int p = 0; p < 16; ++p) {
            const float2 w = *(const float2*)(ws + p * 16 + d * 2);
            hp[p].x = fmaf(w.x, xd, hp[p].x);
            hp[p].y = fmaf(w.y, xd, hp[p].y);
        }
    }
#pragma unroll
    for (int p = 0; p < 16; ++p) {
        hp[p].x = fmaxf(hp[p].x, 0.0f);
        hp[p].y = fmaxf(hp[p].y, 0.0f);
    }
    // LN1 normalize (affine folded into M2'/c2'), paired tree moments
    {
        float2 sa = {0, 0}, sb = {0, 0}, qa = {0, 0}, qb = {0, 0};
#pragma unroll
        for (int p = 0; p < 16; p += 2) {
            sa.x += hp[p].x;     sa.y += hp[p].y;
            sb.x += hp[p + 1].x; sb.y += hp[p + 1].y;
            qa.x = fmaf(hp[p].x, hp[p].x, qa.x);
            qa.y = fmaf(hp[p].y, hp[p].y, qa.y);
            qb.x = fmaf(hp[p + 1].x, hp[p + 1].x, qb.x);
            qb.y = fmaf(hp[p + 1].y, hp[p + 1].y, qb.y);
        }
        const float m   = ((sa.x + sa.y) + (sb.x + sb.y)) * 0.03125f;
        const float msq = ((qa.x + qa.y) + (qb.x + qb.y)) * 0.03125f;
        const float r   = rsqrtf(fmaf(-m, m, msq) + LN_EPS);
        // phase A write: row = lane, slot c swizzled by (lane&7)
        float* const dst = hb + lane * 32;
        const int key3 = lane & 7;
#pragma unroll
        for (int c = 0; c < 8; ++c) {
            *(float4*)(dst + ((c ^ key3) << 2)) =
                make_float4((hp[c * 2].x - m) * r, (hp[c * 2].y - m) * r,
                            (hp[c * 2 + 1].x - m) * r, (hp[c * 2 + 1].y - m) * r);
        }
    }
    __syncthreads();

    // A fragments (activations as arg0 — PROVEN ROLE): A[m][k]=hhat[mt*16+m][k];
    // lane holds m=l15, k=lg*8+i. Full hi/lo split (PRECISION RULE).
    bf16x8 ahi[4], alo[4];
    const int k7 = l15 & 7;   // row swizzle key: (mt*16+l15)&7 == l15&7
#pragma unroll
    for (int mt = 0; mt < 4; ++mt) {
        const float* ap = hb + (mt * 16 + l15) * 32;
        const float4 a0 = *(const float4*)(ap + (((2 * lg) ^ k7) << 2));
        const float4 a1 = *(const float4*)(ap + (((2 * lg + 1) ^ k7) << 2));
        const float av[8] = {a0.x, a0.y, a0.z, a0.w, a1.x, a1.y, a1.z, a1.w};
#pragma unroll
        for (int i = 0; i < 8; ++i) {
            const __bf16 hi = (__bf16)av[i];
            ahi[mt][i] = hi;
            alo[mt][i] = (__bf16)(av[i] - (float)hi);
        }
    }
    __syncthreads();   // all A-frag reads landed before hb is reused as YT

    // stage 2 MFMA: 4 m-tiles x 2 n-tiles, 3-term split; relu; YT write.
#pragma unroll
    for (int mt = 0; mt < 4; ++mt) {
#pragma unroll
        for (int nt = 0; nt < 2; ++nt) {
            const float c2v = nt ? c2b : c2a;
            f32x4 acc = {c2v, c2v, c2v, c2v};
            acc = __builtin_amdgcn_mfma_f32_16x16x32_bf16(ahi[mt], bhi[nt], acc, 0, 0, 0);
            acc = __builtin_amdgcn_mfma_f32_16x16x32_bf16(alo[mt], bhi[nt], acc, 0, 0, 0);
            acc = __builtin_amdgcn_mfma_f32_16x16x32_bf16(ahi[mt], blo[nt], acc, 0, 0, 0);
            // D reg j -> row (lane>>4)*4 + j, col lane&15  (r5-verified)
            float* yt = hb + (nt * 16 + l15) * 64 + (((mt * 4 + lg) ^ l15) << 2);
            *((float4*)yt) = make_float4(fmaxf(acc[0], 0.0f), fmaxf(acc[1], 0.0f),
                                         fmaxf(acc[2], 0.0f), fmaxf(acc[3], 0.0f));
        }
    }
    __syncthreads();

    // LN2 read-back: lane reads its own row m=lane (2 accesses/bank, free);
    // fused single-pass moments with tree partials.
    const int ms = lane >> 2, mo = lane & 3;
    float y[32];
#pragma unroll
    for (int c = 0; c < 32; ++c)
        y[c] = hb[c * 64 + ((ms ^ (c & 15)) << 2) + mo];
    float s0 = 0, s1 = 0, s2 = 0, s3 = 0, q0 = 0, q1 = 0, q2 = 0, q3 = 0;
#pragma unroll
    for (int i = 0; i < 32; i += 4) {
        s0 += y[i];     q0 = fmaf(y[i],     y[i],     q0);
        s1 += y[i + 1]; q1 = fmaf(y[i + 1], y[i + 1], q1);
        s2 += y[i + 2]; q2 = fmaf(y[i + 2], y[i + 2], q2);
        s3 += y[i + 3]; q3 = fmaf(y[i + 3], y[i + 3], q3);
    }
    const float m   = ((s0 + s1) + (s2 + s3)) * 0.03125f;
    const float msq = ((q0 + q1) + (q2 + q3)) * 0.03125f;
    const float r   = rsqrtf(fmaf(-m, m, msq) + LN_EPS);

    float4* ov = (float4*)out + (size_t)row_g * 8;
#pragma unroll
    for (int q = 0; q < 8; ++q) {
        ov[q] = make_float4(fmaf((y[q * 4 + 0] - m) * r, ws[1344 + q * 4 + 0], ws[1376 + q * 4 + 0]),
                            fmaf((y[q * 4 + 1] - m) * r, ws[1344 + q * 4 + 1], ws[1376 + q * 4 + 1]),
                            fmaf((y[q * 4 + 2] - m) * r, ws[1344 + q * 4 + 2], ws[1376 + q * 4 + 2]),
                            fmaf((y[q * 4 + 3] - m) * r, ws[1344 + q * 4 + 3], ws[1376 + q * 4 + 3]));
    }
}

extern "C" void kernel_launch(void* const* d_in, const int* in_sizes, int n_in,
                              void* d_out, int out_size, void* d_ws, size_t ws_size,
                              hipStream_t stream) {
    const float* x   = (const float*)d_in[0];
    const float* adj = (const float*)d_in[1];
    const float* W1  = (const float*)d_in[2];
    const float* b1  = (const float*)d_in[3];
    const float* W2  = (const float*)d_in[4];
    const float* b2  = (const float*)d_in[5];
    const float* g1  = (const float*)d_in[6];
    const float* be1 = (const float*)d_in[7];
    const float* g2  = (const float*)d_in[8];
    const float* be2 = (const float*)d_in[9];
    float* out = (float*)d_out;
    float* ws  = (float*)d_ws;

    gnn_prologue<<<1, 256, 0, stream>>>(adj, W1, b1, W2, b2, g1, be1, g2, be2, ws);

    const int rows = 32 * 2048 * 32;            // 2,097,152
    gnn_main<<<rows / 128, 128, 0, stream>>>(x, ws, out);
}

// Round 18
// 79.868 us; speedup vs baseline: 1.7431x; 1.6980x over previous
//
#include <hip/hip_runtime.h>

#define LN_EPS 1e-5f

// Sizes fixed by the problem: B=32, TF=2048, C=32, D=8, HID=EG=32.
// rows = B*TF*C = 2,097,152 independent rows: x[8] -> M1x+c1 -> relu -> LN ->
// M2'h+c2' -> relu -> LN -> *g2+be2. Adjacency + LN1 affine folded on device.
//
// PROVEN-ROLE RULE (r6-r11): MFMA arg0 = activation fragments read row-wise
// from LDS (r5 pattern); arg1 = baked weight table. Do not swap.
// PRECISION RULE (r12): full 3-term hi/lo split required.
// LAUNCH-SHAPE RULE (r15/r16): 256-thread 4-wave blocks only (~8 WG-slots/CU).
// NO-SHUFFLE RULE (r6-r9, r17): every kernel using __shfl_* failed with
// LN-bounded garbage (even masks 1/2/4); every shuffle-free kernel passed.
// Cross-lane data movement must go through LDS + __syncthreads only.
// r18: r14 + dense-store epilogue via phase-C LDS round-trip (no shuffles):
// row-owner finishes its row in-registers (r14-proven), stages to LDS, then
// 8-lane groups store 1KB-contiguous per instruction (512 -> 128 segments).
//
// d_ws float layout:
//   [0,256)     M1pk: pair-interleaved M1, ws[p*16 + d*2 + e] = M1[2p+e][d]
//   [256,288)   c1  = A@b1   (pairs read as float2)
//   [1312,1344) c2' = A@b2 + (A@W2)@be1
//   [1344,1376) g2
//   [1376,1408) be2
//   u16 [2816,3840)  B-frag bhi: slot (nt*64 + l15*4 + lg)*8+i =
//                    bf16hi(M2'[n=nt*16+l15][k=lg*8+i]),  M2'=(A@W2)*diag(g1)
//   u16 [3840,4864)  B-frag blo: bf16lo residual of the same

typedef float  f32x4  __attribute__((ext_vector_type(4)));
typedef __bf16 bf16x8 __attribute__((ext_vector_type(8)));

__global__ void gnn_prologue(const float* __restrict__ adjacency,
                             const float* __restrict__ W1,
                             const float* __restrict__ b1,
                             const float* __restrict__ W2,
                             const float* __restrict__ b2,
                             const float* __restrict__ g1,
                             const float* __restrict__ be1,
                             const float* __restrict__ g2,
                             const float* __restrict__ be2,
                             float* __restrict__ ws) {
    __shared__ float dis[32];
    __shared__ float na[32][32];
    __shared__ float m2t[32][32];   // A@W2 (g1 folded at bake)
    __shared__ float m1s[32][8];
    const int t = threadIdx.x;
    if (t < 32) {
        float s = 1.0f;  // self-loop contributes 1 to the degree
        for (int j = 0; j < 32; ++j) s += adjacency[t * 32 + j];
        dis[t] = rsqrtf(s + 1e-6f);
    }
    __syncthreads();
    for (int idx = t; idx < 1024; idx += 256) {
        const int i = idx >> 5, j = idx & 31;
        const float a = adjacency[idx] + (i == j ? 1.0f : 0.0f);
        na[i][j] = dis[i] * a * dis[j];
    }
    __syncthreads();
    for (int idx = t; idx < 1024; idx += 256) {     // m2t = na @ W2
        const int i = idx >> 5, k = idx & 31;
        float a = 0.0f;
        for (int j = 0; j < 32; ++j) a += na[i][j] * W2[j * 32 + k];
        m2t[i][k] = a;
    }
    {
        const int i = t >> 3, d = t & 7;            // m1 = na @ W1 (to LDS)
        float a = 0.0f;
        for (int j = 0; j < 32; ++j) a += na[i][j] * W1[j * 8 + d];
        m1s[i][d] = a;
    }
    __syncthreads();
    if (t < 128) {                                   // M1 pk-interleaved bake
        const int p = t >> 3, d = t & 7;
        ws[p * 16 + d * 2]     = m1s[2 * p][d];
        ws[p * 16 + d * 2 + 1] = m1s[2 * p + 1][d];
    }
    if (t < 32) {
        float a1 = 0.0f, a2 = 0.0f, a3 = 0.0f;
        for (int j = 0; j < 32; ++j) {
            a1 += na[t][j] * b1[j];
            a2 += na[t][j] * b2[j];
            a3 += m2t[t][j] * be1[j];
        }
        ws[256 + t]  = a1;          // c1
        ws[1312 + t] = a2 + a3;     // c2'
        ws[1344 + t] = g2[t];
        ws[1376 + t] = be2[t];
    }
    // Bake B fragments (r5-exact): slot (nt, l15, lg) holds k = lg*8+i for
    // n = nt*16 + l15, split into bf16 hi/lo.
    if (t < 128) {
        const int nt  = t >> 6;
        const int l15 = (t >> 2) & 15;
        const int lg  = t & 3;
        const int n   = nt * 16 + l15;
        unsigned short* wsu = (unsigned short*)ws;
        for (int i = 0; i < 8; ++i) {
            const float w  = m2t[n][lg * 8 + i] * g1[lg * 8 + i];
            const __bf16 h = (__bf16)w;
            const __bf16 l = (__bf16)(w - (float)h);
            wsu[2816 + t * 8 + i] = __builtin_bit_cast(unsigned short, h);
            wsu[3840 + t * 8 + i] = __builtin_bit_cast(unsigned short, l);
        }
    }
}

// Main kernel (r14 structure + shuffle-free dense-store epilogue):
// 256 threads = 4 waves, 64 rows/wave. Per-wave LDS = 2048 dwords (8 KB):
//   phase A: hhat[row 0..63][32 dwords], slot c at r*32 + ((c ^ (r&7))<<2)
//   phase B: YT[ch 0..31][64 dwords], elem [ch][m] at
//            ch*64 + (((m>>2) ^ (ch&15))<<2) + (m&3)
//   phase C: finished rows, same layout as phase A.
// Block LDS = 32 KB -> 5 blocks/CU, 20 waves/CU. 5 barriers.
__global__ __launch_bounds__(256, 5) void gnn_main(
        const float* __restrict__ x,
        const float* __restrict__ ws,
        float* __restrict__ out) {
    __shared__ __align__(16) float wbuf[4][2048];

    const int t    = threadIdx.x;
    const int wave = t >> 6;
    const int lane = t & 63;
    const int l15  = lane & 15;
    const int lg   = lane >> 4;
    float* const hb = wbuf[wave];

    // B fragments (weights as arg1 — PROVEN ROLE), baked bf16 hi/lo.
    const unsigned short* wsu = (const unsigned short*)ws;
    const int slot8 = (l15 * 4 + lg) * 8;
    bf16x8 bhi[2], blo[2];
    bhi[0] = *(const bf16x8*)(wsu + 2816 + slot8);
    bhi[1] = *(const bf16x8*)(wsu + 2816 + 512 + slot8);
    blo[0] = *(const bf16x8*)(wsu + 3840 + slot8);
    blo[1] = *(const bf16x8*)(wsu + 3840 + 512 + slot8);
    const float c2a = ws[1312 + l15];
    const float c2b = ws[1312 + 16 + l15];

    const int row_g = blockIdx.x * 256 + t;     // one row per thread
    const float4 p0 = ((const float4*)x)[row_g * 2];
    const float4 p1 = ((const float4*)x)[row_g * 2 + 1];
    const float xr[8] = {p0.x, p0.y, p0.z, p0.w, p1.x, p1.y, p1.z, p1.w};

    // stage 1: h = relu(M1 @ x + c1) on float2 pairs (v_pk_fma_f32 pattern)
    float2 hp[16];
#pragma unroll
    for (int p = 0; p < 16; ++p) hp[p] = *(const float2*)(ws + 256 + p * 2);
#pragma unroll
    for (int d = 0; d < 8; ++d) {
        const float xd = xr[d];
#pragma unroll
        for (int p = 0; p < 16; ++p) {
            const float2 w = *(const float2*)(ws + p * 16 + d * 2);
            hp[p].x = fmaf(w.x, xd, hp[p].x);
            hp[p].y = fmaf(w.y, xd, hp[p].y);
        }
    }
#pragma unroll
    for (int p = 0; p < 16; ++p) {
        hp[p].x = fmaxf(hp[p].x, 0.0f);
        hp[p].y = fmaxf(hp[p].y, 0.0f);
    }
    // LN1 normalize (affine folded into M2'/c2'), paired tree moments
    {
        float2 sa = {0, 0}, sb = {0, 0}, qa = {0, 0}, qb = {0, 0};
#pragma unroll
        for (int p = 0; p < 16; p += 2) {
            sa.x += hp[p].x;     sa.y += hp[p].y;
            sb.x += hp[p + 1].x; sb.y += hp[p + 1].y;
            qa.x = fmaf(hp[p].x, hp[p].x, qa.x);
            qa.y = fmaf(hp[p].y, hp[p].y, qa.y);
            qb.x = fmaf(hp[p + 1].x, hp[p + 1].x, qb.x);
            qb.y = fmaf(hp[p + 1].y, hp[p + 1].y, qb.y);
        }
        const float m   = ((sa.x + sa.y) + (sb.x + sb.y)) * 0.03125f;
        const float msq = ((qa.x + qa.y) + (qb.x + qb.y)) * 0.03125f;
        const float r   = rsqrtf(fmaf(-m, m, msq) + LN_EPS);
        // phase A write: row = lane, slot c swizzled by (lane&7)
        float* const dst = hb + lane * 32;
        const int key3 = lane & 7;
#pragma unroll
        for (int c = 0; c < 8; ++c) {
            *(float4*)(dst + ((c ^ key3) << 2)) =
                make_float4((hp[c * 2].x - m) * r, (hp[c * 2].y - m) * r,
                            (hp[c * 2 + 1].x - m) * r, (hp[c * 2 + 1].y - m) * r);
        }
    }
    __syncthreads();

    // A fragments (activations as arg0 — PROVEN ROLE): A[m][k]=hhat[mt*16+m][k];
    // lane holds m=l15, k=lg*8+i. Full hi/lo split (PRECISION RULE).
    bf16x8 ahi[4], alo[4];
    const int k7 = l15 & 7;   // row swizzle key: (mt*16+l15)&7 == l15&7
#pragma unroll
    for (int mt = 0; mt < 4; ++mt) {
        const float* ap = hb + (mt * 16 + l15) * 32;
        const float4 a0 = *(const float4*)(ap + (((2 * lg) ^ k7) << 2));
        const float4 a1 = *(const float4*)(ap + (((2 * lg + 1) ^ k7) << 2));
        const float av[8] = {a0.x, a0.y, a0.z, a0.w, a1.x, a1.y, a1.z, a1.w};
#pragma unroll
        for (int i = 0; i < 8; ++i) {
            const __bf16 hi = (__bf16)av[i];
            ahi[mt][i] = hi;
            alo[mt][i] = (__bf16)(av[i] - (float)hi);
        }
    }
    __syncthreads();   // all A-frag reads landed before hb is reused as YT

    // stage 2 MFMA: 4 m-tiles x 2 n-tiles, 3-term split; relu; YT write.
#pragma unroll
    for (int mt = 0; mt < 4; ++mt) {
#pragma unroll
        for (int nt = 0; nt < 2; ++nt) {
            const float c2v = nt ? c2b : c2a;
            f32x4 acc = {c2v, c2v, c2v, c2v};
            acc = __builtin_amdgcn_mfma_f32_16x16x32_bf16(ahi[mt], bhi[nt], acc, 0, 0, 0);
            acc = __builtin_amdgcn_mfma_f32_16x16x32_bf16(alo[mt], bhi[nt], acc, 0, 0, 0);
            acc = __builtin_amdgcn_mfma_f32_16x16x32_bf16(ahi[mt], blo[nt], acc, 0, 0, 0);
            // D reg j -> row (lane>>4)*4 + j, col lane&15  (r5-verified)
            float* yt = hb + (nt * 16 + l15) * 64 + (((mt * 4 + lg) ^ l15) << 2);
            *((float4*)yt) = make_float4(fmaxf(acc[0], 0.0f), fmaxf(acc[1], 0.0f),
                                         fmaxf(acc[2], 0.0f), fmaxf(acc[3], 0.0f));
        }
    }
    __syncthreads();

    // LN2 read-back (r14-proven): lane owns row m = lane; in-thread stats;
    // affine applied in-registers.
    const int ms = lane >> 2, mo = lane & 3;
    float y[32];
#pragma unroll
    for (int c = 0; c < 32; ++c)
        y[c] = hb[c * 64 + ((ms ^ (c & 15)) << 2) + mo];
    {
        float s0 = 0, s1 = 0, s2 = 0, s3 = 0, q0 = 0, q1 = 0, q2 = 0, q3 = 0;
#pragma unroll
        for (int i = 0; i < 32; i += 4) {
            s0 += y[i];     q0 = fmaf(y[i],     y[i],     q0);
            s1 += y[i + 1]; q1 = fmaf(y[i + 1], y[i + 1], q1);
            s2 += y[i + 2]; q2 = fmaf(y[i + 2], y[i + 2], q2);
            s3 += y[i + 3]; q3 = fmaf(y[i + 3], y[i + 3], q3);
        }
        const float m   = ((s0 + s1) + (s2 + s3)) * 0.03125f;
        const float msq = ((q0 + q1) + (q2 + q3)) * 0.03125f;
        const float r   = rsqrtf(fmaf(-m, m, msq) + LN_EPS);
#pragma unroll
        for (int c = 0; c < 32; ++c)
            y[c] = fmaf((y[c] - m) * r, ws[1344 + c], ws[1376 + c]);
    }
    __syncthreads();   // barrier 4: all YT reads done before phase C overwrite

    // phase C write: finished row staged like phase A (row=lane, swizzle lane&7)
    {
        float* const dst = hb + lane * 32;
        const int key3 = lane & 7;
#pragma unroll
        for (int c = 0; c < 8; ++c)
            *(float4*)(dst + ((c ^ key3) << 2)) =
                make_float4(y[c * 4], y[c * 4 + 1], y[c * 4 + 2], y[c * 4 + 3]);
    }
    __syncthreads();   // barrier 5: phase C visible

    // Dense store: lane (g8 = lane>>3, c8 = lane&7); per step s the wave
    // stores rows s*8..s*8+7 fully contiguous (1 KB per instruction).
    {
        const int g8 = lane >> 3;
        const int c8 = lane & 7;
        const int wave_row0 = blockIdx.x * 256 + wave * 64;
#pragma unroll
        for (int s = 0; s < 8; ++s) {
            const int r = s * 8 + g8;           // local row; r&7 == g8
            const float4 v = *(const float4*)(hb + r * 32 + ((c8 ^ g8) << 2));
            ((float4*)out)[(size_t)(wave_row0 + r) * 8 + c8] = v;
        }
    }
}

extern "C" void kernel_launch(void* const* d_in, const int* in_sizes, int n_in,
                              void* d_out, int out_size, void* d_ws, size_t ws_size,
                              hipStream_t stream) {
    const float* x   = (const float*)d_in[0];
    const float* adj = (const float*)d_in[1];
    const float* W1  = (const float*)d_in[2];
    const float* b1  = (const float*)d_in[3];
    const float* W2  = (const float*)d_in[4];
    const float* b2  = (const float*)d_in[5];
    const float* g1  = (const float*)d_in[6];
    const float* be1 = (const float*)d_in[7];
    const float* g2  = (const float*)d_in[8];
    const float* be2 = (const float*)d_in[9];
    float* out = (float*)d_out;
    float* ws  = (float*)d_ws;

    gnn_prologue<<<1, 256, 0, stream>>>(adj, W1, b1, W2, b2, g1, be1, g2, be2, ws);

    const int rows = 32 * 2048 * 32;            // 2,097,152
    gnn_main<<<rows / 256, 256, 0, stream>>>(x, ws, out);
}